// Round 16
// baseline (67.991 us; speedup 1.0000x reference)
//
#include <hip/hip_runtime.h>

// Problem constants (fixed by the reference)
#define B_ 512
#define T_ 256
#define C_ 384
#define H_ 64

typedef __bf16 bf16;
typedef bf16  bf16x8 __attribute__((ext_vector_type(8)));
typedef bf16  bf16x2 __attribute__((ext_vector_type(2)));
typedef float f32x4  __attribute__((ext_vector_type(4)));
typedef int   i32x4  __attribute__((ext_vector_type(4)));

#define NCHUNK     3
#define CHUNK_K    128
#define WT3_CHUNK  24576                  // ELEMENTS per K-chunk (3*64*128)
#define WT3_TOTAL  (NCHUNK * WT3_CHUNK)   // 73728 elems = 147456 B

// ---------------- prep: W (fp32 [C][H]) -> wt3 (bf16, STAGING order) ----------------
__global__ void prep_wt3(const float* __restrict__ Wq,
                         const float* __restrict__ Wk,
                         const float* __restrict__ Wv,
                         bf16* __restrict__ wt3)
{
    int idx = blockIdx.x * 256 + threadIdx.x;
    if (idx >= WT3_TOTAL) return;
    int chunk = idx / WT3_CHUNK;
    int rem   = idx % WT3_CHUNK;
    int s     = rem >> 3;              // 16B chunk slot 0..3071
    int e     = rem & 7;
    int mc    = s >> 4;                // mat*64 + col (16 slots per row)
    int kkc   = (s & 15) ^ (mc & 7);   // inverse of slot swizzle
    int mat   = mc >> 6;
    int col   = mc & 63;
    int k     = chunk * CHUNK_K + kkc * 8 + e;
    const float* W = (mat == 0) ? Wq : (mat == 1) ? Wk : Wv;
    wt3[idx] = (bf16)W[k * H_ + col];
}

__device__ __forceinline__ bf16x8 cvt8(float4 a, float4 b)
{
    bf16x8 r;
    r[0] = (bf16)a.x; r[1] = (bf16)a.y; r[2] = (bf16)a.z; r[3] = (bf16)a.w;
    r[4] = (bf16)b.x; r[5] = (bf16)b.y; r[6] = (bf16)b.z; r[7] = (bf16)b.w;
    return r;
}

__device__ __forceinline__ unsigned pack2(float a, float b)
{
    bf16x2 v; v[0] = (bf16)a; v[1] = (bf16)b;
    return __builtin_bit_cast(unsigned, v);
}

// direct HBM/L2 -> LDS, 16B per lane, wave-uniform LDS base + lane*16
__device__ __forceinline__ void gload_lds16(const bf16* g, bf16* l)
{
    __builtin_amdgcn_global_load_lds(
        (const __attribute__((address_space(1))) void*)g,
        (__attribute__((address_space(3))) void*)l,
        16, 0, 0);
}

// XOR swizzle for k_s / vT_s / p_s: permute 8-elem (16B) chunks within a row.
#define SWZ(row, col) ((col) ^ (((row) & 7) << 3))

// wt_s fragment address: [mc = mat*64+col][kk 0..127] bf16, 16B-chunk swizzled.
__device__ __forceinline__ const bf16x8* wts_frag(const bf16* wt_s, int mc, int kk)
{
    int byte = ((mc * CHUNK_K + kk) * 2) ^ ((mc & 7) << 4);
    return reinterpret_cast<const bf16x8*>(reinterpret_cast<const char*>(wt_s) + byte);
}

// =====================================================================
// R15 structure (verified 65.4us): LDS-union (80KB -> 2 blocks/CU),
// 3x K=128 chunk staging, swapped-QK^T phase 2. This round: phase-2
// softmax in log2 domain (v_exp_f32 IS 2^x -> saves a mul per exp) and
// tree-shaped max/sum reductions (serial chain 31 -> ~5 deep).
// =====================================================================
template<int USE_WT>
__global__ __launch_bounds__(512, 2)
void head_fused16(const float* __restrict__ x,
                  const float* __restrict__ Wq,
                  const float* __restrict__ Wk,
                  const float* __restrict__ Wv,
                  const bf16* __restrict__ wt3,
                  float* __restrict__ out)
{
    __shared__ bf16 lds_u[32768];       // 64KB union
    __shared__ bf16 p_s[8 * 16 * 64];   // 16KB per-wave bounce (q transpose only)

    bf16* wt_s = lds_u;                 // phase-1 view: 24576 elems (48KB) used
    bf16* k_s  = lds_u;                 // phase-2 view: [t=256][h=64] swizzled
    bf16* vT_s = lds_u + 16384;         // phase-2 view: [h=64][t=256] swizzled

    const int tid  = threadIdx.x;
    const int wave = tid >> 6;
    const int lane = tid & 63;
    const int lr   = lane & 15;
    const int lg   = lane >> 4;

    const int b = blockIdx.x;
    const float* xb = x + (size_t)b * T_ * C_;
    bf16* pw = &p_s[wave * 16 * 64];

    const int mt0 = wave, mt1 = 15 - wave;
    bf16x8 qf[2][2];   // q fragments (same layout works as A or B operand)

    // ---------------- Phase 1: q,k,v projections (x read ONCE) ----------------
    f32x4 acc[2][3][4];   // [tile][q,k,v][nw]
    #pragma unroll
    for (int t = 0; t < 2; ++t)
        #pragma unroll
        for (int a = 0; a < 3; ++a)
            #pragma unroll
            for (int nw = 0; nw < 4; ++nw)
                acc[t][a][nw] = (f32x4){0.f, 0.f, 0.f, 0.f};

    #pragma unroll 1
    for (int chunk = 0; chunk < NCHUNK; ++chunk) {
        if (chunk) __syncthreads();   // previous wt_s consumers done
        if (USE_WT) {
            #pragma unroll
            for (int c = 0; c < 6; ++c) {
                const bf16* g = wt3 + chunk * WT3_CHUNK + (c * 512 + tid) * 8;
                bf16* l = wt_s + (c * 512 + wave * 64) * 8;   // linear dest
                gload_lds16(g, l);
            }
        } else {
            #pragma unroll
            for (int c = 0; c < 6; ++c) {
                int f16 = c * 512 + tid;       // slot 0..3071
                int mc  = f16 >> 4;
                int kkc = f16 & 15;
                int mat = mc >> 6, col = mc & 63;
                const float* W = (mat == 0) ? Wq : (mat == 1) ? Wk : Wv;
                bf16x8 vv;
                #pragma unroll
                for (int j = 0; j < 8; ++j)
                    vv[j] = (bf16)W[(chunk * CHUNK_K + kkc * 8 + j) * H_ + col];
                int byte = ((mc * CHUNK_K + kkc * 8) * 2) ^ ((mc & 7) << 4);
                *reinterpret_cast<bf16x8*>(reinterpret_cast<char*>(wt_s) + byte) = vv;
            }
        }

        // prefetch ks=0's x (16 VGPRs) so its HBM latency overlaps the stage drain
        const float* xr0 = xb + (mt0 * 16 + lr) * C_ + chunk * CHUNK_K + lg * 8;
        const float* xr1 = xb + (mt1 * 16 + lr) * C_ + chunk * CHUNK_K + lg * 8;
        float4 p0 = *reinterpret_cast<const float4*>(xr0);
        float4 p1 = *reinterpret_cast<const float4*>(xr0 + 4);
        float4 p2 = *reinterpret_cast<const float4*>(xr1);
        float4 p3 = *reinterpret_cast<const float4*>(xr1 + 4);

        __syncthreads();   // wt_s ready (barrier drains vmcnt, x prefetch too)

        #pragma unroll
        for (int ks = 0; ks < 4; ++ks) {
            float4 a0, a1, b0, b1;
            if (ks == 0) { a0 = p0; a1 = p1; b0 = p2; b1 = p3; }
            else {
                a0 = *reinterpret_cast<const float4*>(xr0 + ks * 32);
                a1 = *reinterpret_cast<const float4*>(xr0 + ks * 32 + 4);
                b0 = *reinterpret_cast<const float4*>(xr1 + ks * 32);
                b1 = *reinterpret_cast<const float4*>(xr1 + ks * 32 + 4);
            }
            bf16x8 af0 = cvt8(a0, a1);
            bf16x8 af1 = cvt8(b0, b1);
            const int kk = ks * 32 + lg * 8;
            #pragma unroll
            for (int mat = 0; mat < 3; ++mat) {
                #pragma unroll
                for (int nw = 0; nw < 4; ++nw) {
                    bf16x8 bfr = *wts_frag(wt_s, mat * 64 + nw * 16 + lr, kk);
                    acc[0][mat][nw] = __builtin_amdgcn_mfma_f32_16x16x32_bf16(
                        af0, bfr, acc[0][mat][nw], 0, 0, 0);
                    acc[1][mat][nw] = __builtin_amdgcn_mfma_f32_16x16x32_bf16(
                        af1, bfr, acc[1][mat][nw], 0, 0, 0);
                }
            }
        }
    }
    __syncthreads();   // ALL waves done with wt_s -> union may be overwritten

    // ---- epilogue: k/vT into the union, q through per-wave bounce ----
    #pragma unroll
    for (int tile = 0; tile < 2; ++tile) {
        const int mt = tile ? mt1 : mt0;
        #pragma unroll
        for (int nw = 0; nw < 4; ++nw) {
            #pragma unroll
            for (int r = 0; r < 4; ++r) {
                int row = mt * 16 + lg * 4 + r;   // t
                int col = nw * 16 + lr;           // h
                k_s[row * 64 + SWZ(row, col)]   = (bf16)acc[tile][1][nw][r];
                vT_s[col * 256 + SWZ(col, row)] = (bf16)acc[tile][2][nw][r];
            }
        }
        #pragma unroll
        for (int nw = 0; nw < 4; ++nw) {
            #pragma unroll
            for (int r = 0; r < 4; ++r) {
                int row = lg * 4 + r;
                pw[row * 64 + SWZ(row, nw * 16 + lr)] = (bf16)acc[tile][0][nw][r];
            }
        }
        asm volatile("s_waitcnt lgkmcnt(0)" ::: "memory");
        __builtin_amdgcn_sched_barrier(0);
        qf[tile][0] = *reinterpret_cast<const bf16x8*>(&pw[lr * 64 + SWZ(lr, lg * 8)]);
        qf[tile][1] = *reinterpret_cast<const bf16x8*>(&pw[lr * 64 + SWZ(lr, 32 + lg * 8)]);
        asm volatile("s_waitcnt lgkmcnt(0)" ::: "memory");
        __builtin_amdgcn_sched_barrier(0);   // reads land before next tile reuses pw
    }
    __syncthreads();   // k_s / vT_s complete

    // ---------------- Phase 2: swapped QK^T causal attention ----------------
    // Scores in LOG2 domain: scale folds in log2(e); v_exp_f32 is natively 2^x.
    const float scale = 0.051031036307982884f * 1.4426950408889634f;

    #pragma unroll
    for (int p = 0; p < 2; ++p) {
        const int mt  = p ? mt1 : mt0;
        const int nkt = mt + 1;                   // valid key tiles

        float m = -1e30f, l = 0.f;
        f32x4 oacc[4];
        #pragma unroll
        for (int n = 0; n < 4; ++n) oacc[n] = (f32x4){0.f, 0.f, 0.f, 0.f};

        #pragma unroll
        for (int h = 0; h < 2; ++h) {
            const int vh = (nkt - h * 8) < 8 ? (nkt - h * 8) : 8;   // valid tiles in half
            if (vh > 0) {   // wave-uniform
                float s[8][4];
                #pragma unroll
                for (int j = 0; j < 8; ++j) {
                    const int kt = h * 8 + j;
                    if (j < vh) {   // wave-uniform
                        bf16x8 kf0 = *reinterpret_cast<const bf16x8*>(
                            &k_s[(kt * 16 + lr) * 64 + SWZ(lr, lg * 8)]);
                        bf16x8 kf1 = *reinterpret_cast<const bf16x8*>(
                            &k_s[(kt * 16 + lr) * 64 + SWZ(lr, 32 + lg * 8)]);
                        f32x4 sc = (f32x4){0.f, 0.f, 0.f, 0.f};
                        sc = __builtin_amdgcn_mfma_f32_16x16x32_bf16(kf0, qf[p][0], sc, 0, 0, 0);
                        sc = __builtin_amdgcn_mfma_f32_16x16x32_bf16(kf1, qf[p][1], sc, 0, 0, 0);
                        #pragma unroll
                        for (int r = 0; r < 4; ++r) {
                            float v = sc[r] * scale;
                            // diag tile: t_local = lg*4+r, q = lr; mask t > q
                            if (kt == mt && (lg * 4 + r) > lr) v = -1e30f;
                            s[j][r] = v;
                        }
                    } else {
                        #pragma unroll
                        for (int r = 0; r < 4; ++r) s[j][r] = -1e30f;
                    }
                }

                // ---- max: per-j depth-2 triples, then pairwise tree (depth ~5) ----
                float mj[8];
                #pragma unroll
                for (int j = 0; j < 8; ++j)
                    mj[j] = fmaxf(fmaxf(s[j][0], s[j][1]), fmaxf(s[j][2], s[j][3]));
                float pm = fmaxf(fmaxf(fmaxf(mj[0], mj[1]), fmaxf(mj[2], mj[3])),
                                 fmaxf(fmaxf(mj[4], mj[5]), fmaxf(mj[6], mj[7])));
                pm = fmaxf(pm, __shfl_xor(pm, 16));
                pm = fmaxf(pm, __shfl_xor(pm, 32));
                float nm = fmaxf(m, pm);
                float fr = exp2f(m - nm);   // 0 on first valid half
                m = nm;
                l *= fr;
                #pragma unroll
                for (int n = 0; n < 4; ++n)
                    #pragma unroll
                    for (int r = 0; r < 4; ++r) oacc[n][r] *= fr;

                // ---- exp2 + sum with 4 parallel accumulators ----
                float t0 = 0.f, t1 = 0.f, t2 = 0.f, t3 = 0.f;
                #pragma unroll
                for (int j = 0; j < 8; ++j) {
                    float e0 = exp2f(s[j][0] - m);
                    float e1 = exp2f(s[j][1] - m);
                    float e2 = exp2f(s[j][2] - m);
                    float e3 = exp2f(s[j][3] - m);
                    s[j][0] = e0; s[j][1] = e1; s[j][2] = e2; s[j][3] = e3;
                    t0 += e0; t1 += e1; t2 += e2; t3 += e3;
                }
                float tt = (t0 + t1) + (t2 + t3);
                tt += __shfl_xor(tt, 16);
                tt += __shfl_xor(tt, 32);
                l += tt;

                // ---- PV: out^T = V^T . P^T; P B-frag via register shuffles ----
                const int nkk = (vh + 1) >> 1;
                #pragma unroll
                for (int kkl = 0; kkl < 4; ++kkl) {
                    if (kkl < nkk) {   // wave-uniform
                        const int kk = h * 4 + kkl;
                        unsigned lo0 = pack2(s[2*kkl][0],   s[2*kkl][1]);
                        unsigned hi0 = pack2(s[2*kkl][2],   s[2*kkl][3]);
                        unsigned lo1 = pack2(s[2*kkl+1][0], s[2*kkl+1][1]);
                        unsigned hi1 = pack2(s[2*kkl+1][2], s[2*kkl+1][3]);
                        // target lane (lr,lg), elem j: t = kk*32 + lg*8 + j
                        //   src lane = (lg&1)*32 + (j>>2)*16 + lr, tile = lg>>1, r = j&3
                        const int src0 = (lg & 1) * 32 + lr;
                        const int src1 = src0 + 16;
                        const bool t1_ = (lg >> 1) != 0;
                        int a0 = __shfl((int)lo0, src0), a1 = __shfl((int)lo1, src0);
                        unsigned w0 = t1_ ? (unsigned)a1 : (unsigned)a0;
                        int b0 = __shfl((int)hi0, src0), b1 = __shfl((int)hi1, src0);
                        unsigned w1 = t1_ ? (unsigned)b1 : (unsigned)b0;
                        int c0 = __shfl((int)lo0, src1), c1 = __shfl((int)lo1, src1);
                        unsigned w2 = t1_ ? (unsigned)c1 : (unsigned)c0;
                        int d0 = __shfl((int)hi0, src1), d1 = __shfl((int)hi1, src1);
                        unsigned w3 = t1_ ? (unsigned)d1 : (unsigned)d0;
                        i32x4 wi = {(int)w0, (int)w1, (int)w2, (int)w3};
                        bf16x8 pf = __builtin_bit_cast(bf16x8, wi);
                        #pragma unroll
                        for (int n = 0; n < 4; ++n) {
                            bf16x8 vf = *reinterpret_cast<const bf16x8*>(
                                &vT_s[(n * 16 + lr) * 256 + SWZ(lr, kk * 32 + lg * 8)]);
                            oacc[n] = __builtin_amdgcn_mfma_f32_16x16x32_bf16(vf, pf, oacc[n], 0, 0, 0);
                        }
                    }
                }
            }
        }

        // epilogue: D[h_local=lg*4+r][q=lr] -> coalesced float4 stores
        const float rin = 1.0f / l;
        float* op = out + ((size_t)b * T_ + mt * 16 + lr) * H_;
        #pragma unroll
        for (int n = 0; n < 4; ++n) {
            float4 st;
            st.x = oacc[n][0] * rin;
            st.y = oacc[n][1] * rin;
            st.z = oacc[n][2] * rin;
            st.w = oacc[n][3] * rin;
            *reinterpret_cast<float4*>(op + n * 16 + lg * 4) = st;
        }
    }
}

extern "C" void kernel_launch(void* const* d_in, const int* in_sizes, int n_in,
                              void* d_out, int out_size, void* d_ws, size_t ws_size,
                              hipStream_t stream)
{
    (void)in_sizes; (void)n_in; (void)out_size;
    const float* x  = (const float*)d_in[0];
    const float* Wq = (const float*)d_in[1];
    const float* Wk = (const float*)d_in[2];
    const float* Wv = (const float*)d_in[3];
    float* o = (float*)d_out;

    if (ws_size >= (size_t)(WT3_TOTAL * sizeof(bf16))) {
        bf16* wt3 = (bf16*)d_ws;
        prep_wt3<<<dim3((WT3_TOTAL + 255) / 256), dim3(256), 0, stream>>>(Wq, Wk, Wv, wt3);
        head_fused16<1><<<dim3(B_), dim3(512), 0, stream>>>(x, Wq, Wk, Wv, wt3, o);
    } else {
        head_fused16<0><<<dim3(B_), dim3(512), 0, stream>>>(x, Wq, Wk, Wv, nullptr, o);
    }
}

// Round 17
// 64.439 us; speedup vs baseline: 1.0551x; 1.0551x over previous
//
#include <hip/hip_runtime.h>

// Problem constants (fixed by the reference)
#define B_ 512
#define T_ 256
#define C_ 384
#define H_ 64

typedef __bf16 bf16;
typedef bf16  bf16x8 __attribute__((ext_vector_type(8)));
typedef bf16  bf16x2 __attribute__((ext_vector_type(2)));
typedef float f32x4  __attribute__((ext_vector_type(4)));
typedef int   i32x4  __attribute__((ext_vector_type(4)));

#define NCHUNK     3
#define CHUNK_K    128
#define WT3_CHUNK  24576                  // ELEMENTS per K-chunk (3*64*128)
#define WT3_TOTAL  (NCHUNK * WT3_CHUNK)   // 73728 elems = 147456 B

// ---------------- prep: W (fp32 [C][H]) -> wt3 (bf16, STAGING order) ----------------
// wt3 holds 16B chunks in slot order s = mc*16 + (kkc^(mc&7)) per K-chunk, so a
// LINEAR global_load_lds copy produces the swizzled wt_s image.
__global__ void prep_wt3(const float* __restrict__ Wq,
                         const float* __restrict__ Wk,
                         const float* __restrict__ Wv,
                         bf16* __restrict__ wt3)
{
    int idx = blockIdx.x * 256 + threadIdx.x;
    if (idx >= WT3_TOTAL) return;
    int chunk = idx / WT3_CHUNK;
    int rem   = idx % WT3_CHUNK;
    int s     = rem >> 3;              // 16B chunk slot 0..3071
    int e     = rem & 7;
    int mc    = s >> 4;                // mat*64 + col (16 slots per row)
    int kkc   = (s & 15) ^ (mc & 7);   // inverse of slot swizzle
    int mat   = mc >> 6;
    int col   = mc & 63;
    int k     = chunk * CHUNK_K + kkc * 8 + e;
    const float* W = (mat == 0) ? Wq : (mat == 1) ? Wk : Wv;
    wt3[idx] = (bf16)W[k * H_ + col];
}

__device__ __forceinline__ bf16x8 cvt8(float4 a, float4 b)
{
    bf16x8 r;
    r[0] = (bf16)a.x; r[1] = (bf16)a.y; r[2] = (bf16)a.z; r[3] = (bf16)a.w;
    r[4] = (bf16)b.x; r[5] = (bf16)b.y; r[6] = (bf16)b.z; r[7] = (bf16)b.w;
    return r;
}

__device__ __forceinline__ unsigned pack2(float a, float b)
{
    bf16x2 v; v[0] = (bf16)a; v[1] = (bf16)b;
    return __builtin_bit_cast(unsigned, v);
}

// direct HBM/L2 -> LDS, 16B per lane, wave-uniform LDS base + lane*16
__device__ __forceinline__ void gload_lds16(const bf16* g, bf16* l)
{
    __builtin_amdgcn_global_load_lds(
        (const __attribute__((address_space(1))) void*)g,
        (__attribute__((address_space(3))) void*)l,
        16, 0, 0);
}

// XOR swizzle for k_s / vT_s / p_s: permute 8-elem (16B) chunks within a row.
#define SWZ(row, col) ((col) ^ (((row) & 7) << 3))

// wt_s fragment address: [mc = mat*64+col][kk 0..127] bf16, 16B-chunk swizzled.
__device__ __forceinline__ const bf16x8* wts_frag(const bf16* wt_s, int mc, int kk)
{
    int byte = ((mc * CHUNK_K + kk) * 2) ^ ((mc & 7) << 4);
    return reinterpret_cast<const bf16x8*>(reinterpret_cast<const char*>(wt_s) + byte);
}

// =====================================================================
// R12 (verified best, 64.9us): LDS-union (80KB -> 2 blocks/CU, 4 waves/
// SIMD), 3x K=128 chunk staging via global_load_lds, swapped-QK^T phase 2
// (lane-local softmax rows, shuffle-assembled P, coalesced f4 stores).
// R13/R15/R16 probes (dbuf, prefetch, log2-softmax) all flat/worse ->
// this is the structure's optimum; reverting to it exactly.
// =====================================================================
template<int USE_WT>
__global__ __launch_bounds__(512, 2)
void head_fused17(const float* __restrict__ x,
                  const float* __restrict__ Wq,
                  const float* __restrict__ Wk,
                  const float* __restrict__ Wv,
                  const bf16* __restrict__ wt3,
                  float* __restrict__ out)
{
    __shared__ bf16 lds_u[32768];       // 64KB union
    __shared__ bf16 p_s[8 * 16 * 64];   // 16KB per-wave bounce (q transpose only)

    bf16* wt_s = lds_u;                 // phase-1 view: 24576 elems (48KB) used
    bf16* k_s  = lds_u;                 // phase-2 view: [t=256][h=64] swizzled
    bf16* vT_s = lds_u + 16384;         // phase-2 view: [h=64][t=256] swizzled

    const int tid  = threadIdx.x;
    const int wave = tid >> 6;
    const int lane = tid & 63;
    const int lr   = lane & 15;
    const int lg   = lane >> 4;

    const int b = blockIdx.x;
    const float* xb = x + (size_t)b * T_ * C_;
    bf16* pw = &p_s[wave * 16 * 64];

    const int mt0 = wave, mt1 = 15 - wave;
    bf16x8 qf[2][2];   // q fragments (same layout works as A or B operand)

    // ---------------- Phase 1: q,k,v projections (x read ONCE) ----------------
    f32x4 acc[2][3][4];   // [tile][q,k,v][nw]
    #pragma unroll
    for (int t = 0; t < 2; ++t)
        #pragma unroll
        for (int a = 0; a < 3; ++a)
            #pragma unroll
            for (int nw = 0; nw < 4; ++nw)
                acc[t][a][nw] = (f32x4){0.f, 0.f, 0.f, 0.f};

    #pragma unroll 1
    for (int chunk = 0; chunk < NCHUNK; ++chunk) {
        if (chunk) __syncthreads();   // previous wt_s consumers done
        if (USE_WT) {
            #pragma unroll
            for (int c = 0; c < 6; ++c) {
                const bf16* g = wt3 + chunk * WT3_CHUNK + (c * 512 + tid) * 8;
                bf16* l = wt_s + (c * 512 + wave * 64) * 8;   // linear dest
                gload_lds16(g, l);
            }
        } else {
            #pragma unroll
            for (int c = 0; c < 6; ++c) {
                int f16 = c * 512 + tid;       // slot 0..3071
                int mc  = f16 >> 4;
                int kkc = f16 & 15;
                int mat = mc >> 6, col = mc & 63;
                const float* W = (mat == 0) ? Wq : (mat == 1) ? Wk : Wv;
                bf16x8 vv;
                #pragma unroll
                for (int j = 0; j < 8; ++j)
                    vv[j] = (bf16)W[(chunk * CHUNK_K + kkc * 8 + j) * H_ + col];
                int byte = ((mc * CHUNK_K + kkc * 8) * 2) ^ ((mc & 7) << 4);
                *reinterpret_cast<bf16x8*>(reinterpret_cast<char*>(wt_s) + byte) = vv;
            }
        }
        __syncthreads();   // wt_s ready (barrier drains vmcnt)

        const float* xr0 = xb + (mt0 * 16 + lr) * C_ + chunk * CHUNK_K + lg * 8;
        const float* xr1 = xb + (mt1 * 16 + lr) * C_ + chunk * CHUNK_K + lg * 8;
        #pragma unroll
        for (int ks = 0; ks < 4; ++ks) {
            float4 a0 = *reinterpret_cast<const float4*>(xr0 + ks * 32);
            float4 a1 = *reinterpret_cast<const float4*>(xr0 + ks * 32 + 4);
            float4 b0 = *reinterpret_cast<const float4*>(xr1 + ks * 32);
            float4 b1 = *reinterpret_cast<const float4*>(xr1 + ks * 32 + 4);
            bf16x8 af0 = cvt8(a0, a1);
            bf16x8 af1 = cvt8(b0, b1);
            const int kk = ks * 32 + lg * 8;
            #pragma unroll
            for (int mat = 0; mat < 3; ++mat) {
                #pragma unroll
                for (int nw = 0; nw < 4; ++nw) {
                    bf16x8 bfr = *wts_frag(wt_s, mat * 64 + nw * 16 + lr, kk);
                    acc[0][mat][nw] = __builtin_amdgcn_mfma_f32_16x16x32_bf16(
                        af0, bfr, acc[0][mat][nw], 0, 0, 0);
                    acc[1][mat][nw] = __builtin_amdgcn_mfma_f32_16x16x32_bf16(
                        af1, bfr, acc[1][mat][nw], 0, 0, 0);
                }
            }
        }
    }
    __syncthreads();   // ALL waves done with wt_s -> union may be overwritten

    // ---- epilogue: k/vT into the union, q through per-wave bounce ----
    #pragma unroll
    for (int tile = 0; tile < 2; ++tile) {
        const int mt = tile ? mt1 : mt0;
        #pragma unroll
        for (int nw = 0; nw < 4; ++nw) {
            #pragma unroll
            for (int r = 0; r < 4; ++r) {
                int row = mt * 16 + lg * 4 + r;   // t
                int col = nw * 16 + lr;           // h
                k_s[row * 64 + SWZ(row, col)]   = (bf16)acc[tile][1][nw][r];
                vT_s[col * 256 + SWZ(col, row)] = (bf16)acc[tile][2][nw][r];
            }
        }
        #pragma unroll
        for (int nw = 0; nw < 4; ++nw) {
            #pragma unroll
            for (int r = 0; r < 4; ++r) {
                int row = lg * 4 + r;
                pw[row * 64 + SWZ(row, nw * 16 + lr)] = (bf16)acc[tile][0][nw][r];
            }
        }
        asm volatile("s_waitcnt lgkmcnt(0)" ::: "memory");
        __builtin_amdgcn_sched_barrier(0);
        qf[tile][0] = *reinterpret_cast<const bf16x8*>(&pw[lr * 64 + SWZ(lr, lg * 8)]);
        qf[tile][1] = *reinterpret_cast<const bf16x8*>(&pw[lr * 64 + SWZ(lr, 32 + lg * 8)]);
        asm volatile("s_waitcnt lgkmcnt(0)" ::: "memory");
        __builtin_amdgcn_sched_barrier(0);   // reads land before next tile reuses pw
    }
    __syncthreads();   // k_s / vT_s complete

    // ---------------- Phase 2: swapped QK^T causal attention ----------------
    // sc = mfma(K, Q): lane lr owns score row q=lr. Softmax stats lane-scalar
    // (reduce over lg = shfl_xor 16,32). PV computes out^T = V^T . P^T with
    // P B-frags assembled by register shuffles; coalesced float4 stores.
    const float scale = 0.051031036307982884f;   // 384^-0.5 (C, not H)

    #pragma unroll
    for (int p = 0; p < 2; ++p) {
        const int mt  = p ? mt1 : mt0;
        const int nkt = mt + 1;                   // valid key tiles

        float m = -1e30f, l = 0.f;
        f32x4 oacc[4];
        #pragma unroll
        for (int n = 0; n < 4; ++n) oacc[n] = (f32x4){0.f, 0.f, 0.f, 0.f};

        #pragma unroll
        for (int h = 0; h < 2; ++h) {
            const int vh = (nkt - h * 8) < 8 ? (nkt - h * 8) : 8;   // valid tiles in half
            if (vh > 0) {   // wave-uniform
                float s[8][4];
                #pragma unroll
                for (int j = 0; j < 8; ++j) {
                    const int kt = h * 8 + j;
                    if (j < vh) {   // wave-uniform
                        bf16x8 kf0 = *reinterpret_cast<const bf16x8*>(
                            &k_s[(kt * 16 + lr) * 64 + SWZ(lr, lg * 8)]);
                        bf16x8 kf1 = *reinterpret_cast<const bf16x8*>(
                            &k_s[(kt * 16 + lr) * 64 + SWZ(lr, 32 + lg * 8)]);
                        f32x4 sc = (f32x4){0.f, 0.f, 0.f, 0.f};
                        sc = __builtin_amdgcn_mfma_f32_16x16x32_bf16(kf0, qf[p][0], sc, 0, 0, 0);
                        sc = __builtin_amdgcn_mfma_f32_16x16x32_bf16(kf1, qf[p][1], sc, 0, 0, 0);
                        #pragma unroll
                        for (int r = 0; r < 4; ++r) {
                            float v = sc[r] * scale;
                            // diag tile: t_local = lg*4+r, q = lr; mask t > q
                            if (kt == mt && (lg * 4 + r) > lr) v = -1e30f;
                            s[j][r] = v;
                        }
                    } else {
                        #pragma unroll
                        for (int r = 0; r < 4; ++r) s[j][r] = -1e30f;
                    }
                }

                // ---- softmax stats: row q=lr is lane-local + lg-spread ----
                float pm = s[0][0];
                #pragma unroll
                for (int j = 0; j < 8; ++j)
                    #pragma unroll
                    for (int r = 0; r < 4; ++r) pm = fmaxf(pm, s[j][r]);
                pm = fmaxf(pm, __shfl_xor(pm, 16));
                pm = fmaxf(pm, __shfl_xor(pm, 32));
                float nm = fmaxf(m, pm);
                float fr = __expf(m - nm);   // 0 on first valid half
                m = nm;
                l *= fr;
                #pragma unroll
                for (int n = 0; n < 4; ++n)
                    #pragma unroll
                    for (int r = 0; r < 4; ++r) oacc[n][r] *= fr;

                float tt = 0.f;
                #pragma unroll
                for (int j = 0; j < 8; ++j)
                    #pragma unroll
                    for (int r = 0; r < 4; ++r) {
                        float e = __expf(s[j][r] - m);
                        s[j][r] = e;
                        tt += e;
                    }
                tt += __shfl_xor(tt, 16);
                tt += __shfl_xor(tt, 32);
                l += tt;

                // ---- PV: out^T = V^T . P^T; P B-frag via register shuffles ----
                const int nkk = (vh + 1) >> 1;
                #pragma unroll
                for (int kkl = 0; kkl < 4; ++kkl) {
                    if (kkl < nkk) {   // wave-uniform
                        const int kk = h * 4 + kkl;
                        unsigned lo0 = pack2(s[2*kkl][0],   s[2*kkl][1]);
                        unsigned hi0 = pack2(s[2*kkl][2],   s[2*kkl][3]);
                        unsigned lo1 = pack2(s[2*kkl+1][0], s[2*kkl+1][1]);
                        unsigned hi1 = pack2(s[2*kkl+1][2], s[2*kkl+1][3]);
                        // target lane (lr,lg), elem j: t = kk*32 + lg*8 + j
                        //   src lane = (lg&1)*32 + (j>>2)*16 + lr, tile = lg>>1, r = j&3
                        const int src0 = (lg & 1) * 32 + lr;
                        const int src1 = src0 + 16;
                        const bool t1  = (lg >> 1) != 0;
                        int a0 = __shfl((int)lo0, src0), a1 = __shfl((int)lo1, src0);
                        unsigned w0 = t1 ? (unsigned)a1 : (unsigned)a0;
                        int b0 = __shfl((int)hi0, src0), b1 = __shfl((int)hi1, src0);
                        unsigned w1 = t1 ? (unsigned)b1 : (unsigned)b0;
                        int c0 = __shfl((int)lo0, src1), c1 = __shfl((int)lo1, src1);
                        unsigned w2 = t1 ? (unsigned)c1 : (unsigned)c0;
                        int d0 = __shfl((int)hi0, src1), d1 = __shfl((int)hi1, src1);
                        unsigned w3 = t1 ? (unsigned)d1 : (unsigned)d0;
                        i32x4 wi = {(int)w0, (int)w1, (int)w2, (int)w3};
                        bf16x8 pf = __builtin_bit_cast(bf16x8, wi);
                        #pragma unroll
                        for (int n = 0; n < 4; ++n) {
                            bf16x8 vf = *reinterpret_cast<const bf16x8*>(
                                &vT_s[(n * 16 + lr) * 256 + SWZ(lr, kk * 32 + lg * 8)]);
                            // A = V^T rows (h), B = P^T cols (q)
                            oacc[n] = __builtin_amdgcn_mfma_f32_16x16x32_bf16(vf, pf, oacc[n], 0, 0, 0);
                        }
                    }
                }
            }
        }

        // epilogue: D[h_local=lg*4+r][q=lr] -> coalesced float4 stores
        const float rin = 1.0f / l;
        float* op = out + ((size_t)b * T_ + mt * 16 + lr) * H_;
        #pragma unroll
        for (int n = 0; n < 4; ++n) {
            float4 st;
            st.x = oacc[n][0] * rin;
            st.y = oacc[n][1] * rin;
            st.z = oacc[n][2] * rin;
            st.w = oacc[n][3] * rin;
            *reinterpret_cast<float4*>(op + n * 16 + lg * 4) = st;
        }
    }
}

extern "C" void kernel_launch(void* const* d_in, const int* in_sizes, int n_in,
                              void* d_out, int out_size, void* d_ws, size_t ws_size,
                              hipStream_t stream)
{
    (void)in_sizes; (void)n_in; (void)out_size;
    const float* x  = (const float*)d_in[0];
    const float* Wq = (const float*)d_in[1];
    const float* Wk = (const float*)d_in[2];
    const float* Wv = (const float*)d_in[3];
    float* o = (float*)d_out;

    if (ws_size >= (size_t)(WT3_TOTAL * sizeof(bf16))) {
        bf16* wt3 = (bf16*)d_ws;
        prep_wt3<<<dim3((WT3_TOTAL + 255) / 256), dim3(256), 0, stream>>>(Wq, Wk, Wv, wt3);
        head_fused17<1><<<dim3(B_), dim3(512), 0, stream>>>(x, Wq, Wk, Wv, wt3, o);
    } else {
        head_fused17<0><<<dim3(B_), dim3(512), 0, stream>>>(x, Wq, Wk, Wv, nullptr, o);
    }
}